// Round 1
// baseline (131.326 us; speedup 1.0000x reference)
//
#include <hip/hip_runtime.h>

// Problem constants
#define B_DIM   4096
#define C_DIM   128
#define TOPK    8
#define K_INST  16
#define P_IDS   256          // B/K_INST
#define N_DIM   32768        // B*TOPK
#define INV_TEMP 20.0f       // 1/0.05
#define EPS 1e-6f
#define TSZ 8192             // u16 elements per 16 KB A-tile LDS buffer (64 rows x 128)

typedef unsigned short u16;
typedef __attribute__((ext_vector_type(8))) short bf16x8;
typedef __attribute__((ext_vector_type(4))) float f32x4;

struct alignas(8) U16x4 { u16 x, y, z, w; };

__device__ __forceinline__ u16 f2bf(float x) {
    union { float f; unsigned u; } v; v.f = x;
    unsigned r = v.u + 0x7fffu + ((v.u >> 16) & 1u);   // RTN-even
    return (u16)(r >> 16);
}

__device__ __forceinline__ void gload_lds16(const u16* g, u16* l) {
    __builtin_amdgcn_global_load_lds(
        (__attribute__((address_space(1))) void*)g,
        (__attribute__((address_space(3))) void*)l,
        16, 0, 0);
}

// ---------------- kernel 1: fp32 -> bf16 convert (A only, 1 MB out) ----------------
#define NA4 131072           // 4096*128/4
__global__ __launch_bounds__(256) void convert_bf16(const float4* __restrict__ fa,
                                                    u16* __restrict__ outA) {
    int i = blockIdx.x * 256 + threadIdx.x;
    float4 v = fa[i];
    U16x4 o = { f2bf(v.x), f2bf(v.y), f2bf(v.z), f2bf(v.w) };
    *(U16x4*)(outA + (size_t)i * 4) = o;
}

// ---------------- kernel 2: pipelined sim + per-block max/min ----------------
// R9 vs R8 (115 us total, phase1 44.7 us, MfmaUtil 29, Occupancy 17):
//  * Occupancy 2x: tile halved to 64 rows x 128 cols (LDS 2x16KB = 32 KB),
//    grid (256 p, 4 h quarters), __launch_bounds__(256,4) -> 4 blocks/CU,
//    16 waves/CU. acc shrinks 64->32 VGPRs which is what makes 4 waves/SIMD fit.
//  * kk-phase interleave: per iter, 4 phases of {2 ds_read_b128 -> 8 MFMAs in
//    s_setprio(1/0)}. Fine MFMA/LDS overlap + wave role diversity (T5 needs
//    phases); A-frag liveness 64 -> 8 VGPRs.
//  * Drain vmcnt(2): 4 prefetch DMAs (oldest) drained, 2 epilogue stores stay
//    in flight.
// Retained from R8: swapped MFMA operands (S^T in regs, per-A-row max = fold
// 16 + 2 shuffles, 64B-line stores), XOR-swizzle via global source address,
// B fp32->bf16 in-register.
__global__ __launch_bounds__(256, 4) void phase1(const u16*  __restrict__ A,    // bf16 [4096][128]
                                                 const float* __restrict__ Bm32, // fp32 [32768][128]
                                                 float* __restrict__ pmax,      // [2][256][4096]
                                                 float* __restrict__ pmin)      // [2][4096]
{
    __shared__ u16 Als[2 * TSZ];      // 32 KB double buffer

    const int tid  = threadIdx.x;
    const int lane = tid & 63;
    const int wave = tid >> 6;
    const int wm   = wave >> 1;       // row half of 64-row tile (0/1) -> 32 rows
    const int wn   = wave & 1;        // col half (0/1) -> 64 cols
    const int p    = blockIdx.x;      // identity col-block 0..255
    const int h    = blockIdx.y;      // quarter of B_DIM: rows h*1024..+1023
    const int r    = lane & 15;
    const int g    = lane >> 4;

    // staging: thread stages slots s = j*256+tid (j=0..3); slot s holds global
    // chunk (row = s>>4, kc = (s&15)^((s>>4)&7)); kc is j-invariant since
    // j*16 == 0 (mod 8).
    const int skc = (tid & 15) ^ ((tid >> 4) & 7);
    const u16* sbase = A + ((size_t)h * 1024 + (tid >> 4)) * C_DIM + skc * 8;

    // ---- prologue: DMA tile 0 -> buf0 (async) ----
    {
        u16* dst = &Als[tid * 8];
#pragma unroll
        for (int j = 0; j < 4; ++j)
            gload_lds16(sbase + (size_t)j * 16 * C_DIM, dst + j * 2048);
    }

    // ---- B fragments: fp32 -> bf16 in-register (one-time, 64 VGPRs) ----
    bf16x8 b[4][4];                   // [ni][kk]
    {
        const float* brow = Bm32 + (size_t)(p * 128 + wn * 64 + r) * C_DIM + g * 8;
#pragma unroll
        for (int ni = 0; ni < 4; ++ni)
#pragma unroll
            for (int kk = 0; kk < 4; ++kk) {
                const float* s0 = brow + (size_t)ni * 16 * C_DIM + kk * 32;
                float4 u0 = *(const float4*)s0;
                float4 u1 = *(const float4*)(s0 + 4);
                bf16x8 f;
                f[0] = (short)f2bf(u0.x); f[1] = (short)f2bf(u0.y);
                f[2] = (short)f2bf(u0.z); f[3] = (short)f2bf(u0.w);
                f[4] = (short)f2bf(u1.x); f[5] = (short)f2bf(u1.y);
                f[6] = (short)f2bf(u1.z); f[7] = (short)f2bf(u1.w);
                b[ni][kk] = f;
            }
    }

    // diagonal bookkeeping: identity p's anchor rows = [p*16, p*16+16)
    const bool diag_blk = (h == (p >> 6));
    const int  itd      = (p >> 2) & 15;      // iter holding the anchor rows
    const int  wmsel    = (p >> 1) & 1;       // 32-row half within tile
    const int  misel    = p & 1;              // 16-row group within half
    float* const pmax_w = pmax + ((size_t)wn * P_IDS + p) * B_DIM;

    // A-row addressing for this thread's fragments (rows arow0, arow0+16;
    // same XOR key since +16 preserves row&7)
    const int arow0 = wm * 32 + r;
    const int swz   = arow0 & 7;

    __builtin_amdgcn_s_waitcnt(0);            // prologue DMA + B loads done
    __builtin_amdgcn_s_barrier();

    int lofs = 0;
#pragma unroll 1
    for (int it = 0; it < 16; ++it) {
        // prefetch tile it+1 into the other buffer (overlaps this iter's compute)
        if (it < 15) {
            u16* dst = &Als[(lofs ^ TSZ) + tid * 8];
            const u16* src = sbase + (size_t)(it + 1) * 64 * C_DIM;
#pragma unroll
            for (int j = 0; j < 4; ++j)
                gload_lds16(src + (size_t)j * 16 * C_DIM, dst + j * 2048);
        }

        const int row0 = h * 1024 + it * 64;

        // ---- 4 kk-phases: {2 ds_read_b128 -> 8 MFMAs} , operands swapped ----
        // D[n][m] (S^T tile): col(lane&15) = m-sub (A row), row(g*4+rr) = n-sub
        f32x4 acc[4][2] = {};         // [ni][mi]
#pragma unroll
        for (int kk = 0; kk < 4; ++kk) {
            const int c = ((kk * 4 + g) ^ swz) * 8;
            bf16x8 a0 = *(const bf16x8*)&Als[lofs + arow0 * 128 + c];
            bf16x8 a1 = *(const bf16x8*)&Als[lofs + arow0 * 128 + 16 * 128 + c];
            __builtin_amdgcn_s_setprio(1);
#pragma unroll
            for (int ni = 0; ni < 4; ++ni) {
                acc[ni][0] = __builtin_amdgcn_mfma_f32_16x16x32_bf16(b[ni][kk], a0, acc[ni][0], 0, 0, 0);
                acc[ni][1] = __builtin_amdgcn_mfma_f32_16x16x32_bf16(b[ni][kk], a1, acc[ni][1], 0, 0, 0);
            }
            __builtin_amdgcn_s_setprio(0);
        }

        // ---- epilogue: per-A-row max over this wave's 64 cols ----
        // column m = mi*16 + r: 16 in-register n-values (ni x rr) -> fold 15
        // fmax + 2 shuffles. Lanes 0-15 store one full 64B line per mi.
#pragma unroll
        for (int mi = 0; mi < 2; ++mi) {
            float m = acc[0][mi][0];
#pragma unroll
            for (int ni = 0; ni < 4; ++ni)
#pragma unroll
                for (int rr = 0; rr < 4; ++rr)
                    if (ni || rr) m = fmaxf(m, acc[ni][mi][rr]);
            m = fmaxf(m, __shfl_xor(m, 16, 64));
            m = fmaxf(m, __shfl_xor(m, 32, 64));
            if (lane < 16)
                pmax_w[row0 + wm * 32 + mi * 16 + lane] = m;
        }

        // ---- diagonal min (anchor identity's own rows) ----
        // misel stays COMPILE-TIME into acc (dynamic index -> scratch spill).
        if (diag_blk && it == itd && wm == wmsel) {
            float m = 3.4e38f;
#pragma unroll
            for (int mi = 0; mi < 2; ++mi) {
                if (mi == misel) {
#pragma unroll
                    for (int ni = 0; ni < 4; ++ni)
#pragma unroll
                        for (int rr = 0; rr < 4; ++rr)
                            m = fminf(m, acc[ni][mi][rr]);
                }
            }
            m = fminf(m, __shfl_xor(m, 16, 64));
            m = fminf(m, __shfl_xor(m, 32, 64));
            if (lane < 16)
                pmin[(size_t)wn * B_DIM + p * 16 + lane] = m;
        }

        if (it < 15) {
            // drain ONLY the 4 prefetch DMAs (oldest vmem); epilogue stores
            // (2, newer) stay in flight. vmcnt=2, expcnt=7, lgkmcnt=15.
            __builtin_amdgcn_s_waitcnt(0xF72);
            __builtin_amdgcn_s_barrier();
        }
        lofs ^= TSZ;
    }
}

// ---------------- kernel 3: per-row loss + mean ----------------
// grid 256 blocks x 256 threads; block = 16 rows. Lanes r=0..15 read 64B-line
// chunks of [p][row]; 16 p-groups partial-sum via LDS.
__global__ __launch_bounds__(256) void phase2(const float* __restrict__ pmax,  // [2][256][4096]
                                              const float* __restrict__ pmin,  // [2][4096]
                                              const int* __restrict__ labels,
                                              float* __restrict__ out) {
    const int tid = threadIdx.x;
    const int r   = tid & 15;
    const int pg  = tid >> 4;
    const int row = blockIdx.x * 16 + r;
    const int pid = labels[row];
    const float* q0 = pmax + row;                          // + p*B_DIM
    const float* q1 = q0 + (size_t)P_IDS * B_DIM;
    float s = 0.f;
#pragma unroll
    for (int j = 0; j < 16; ++j) {
        const int p = pg * 16 + j;
        const float v = fmaxf(q0[(size_t)p * B_DIM], q1[(size_t)p * B_DIM]);
        s += (p == pid) ? 0.f : __expf(v * INV_TEMP);
    }
    __shared__ float part[16][17];
    part[pg][r] = s;
    __syncthreads();
    if (tid < 16) {
        float neg = 0.f;
#pragma unroll
        for (int j = 0; j < 16; ++j) neg += part[j][tid];
        const int rw = blockIdx.x * 16 + tid;
        const float mn  = fminf(pmin[rw], pmin[B_DIM + rw]);
        const float pos = __expf(mn * INV_TEMP);
        float loss = -__logf(pos / (pos + neg + EPS) + EPS);
        loss += __shfl_xor(loss, 1, 64);
        loss += __shfl_xor(loss, 2, 64);
        loss += __shfl_xor(loss, 4, 64);
        loss += __shfl_xor(loss, 8, 64);
        if (tid == 0) atomicAdd(out, loss * (1.0f / (float)B_DIM));
    }
}

extern "C" void kernel_launch(void* const* d_in, const int* in_sizes, int n_in,
                              void* d_out, int out_size, void* d_ws, size_t ws_size,
                              hipStream_t stream) {
    const float* feats   = (const float*)d_in[0];   // [4096,128]
    const float* feats_s = (const float*)d_in[1];   // [4096,8,128] fp32 (read directly)
    const int*   labels  = (const int*)d_in[2];     // [4096]
    float* out = (float*)d_out;

    // workspace: bf16 A (1 MB) | pmax (8 MB) | pmin (32 KB)
    u16* wsA = (u16*)d_ws;
    float* pmax = (float*)((char*)d_ws + (1u << 20));
    float* pmin = pmax + (size_t)2 * P_IDS * B_DIM;

    hipMemsetAsync(d_out, 0, sizeof(float), stream);
    convert_bf16<<<NA4 / 256, 256, 0, stream>>>((const float4*)feats, wsA);
    dim3 g1(P_IDS, 4);
    phase1<<<g1, 256, 0, stream>>>(wsA, feats_s, pmax, pmin);
    phase2<<<B_DIM / 16, 256, 0, stream>>>(pmax, pmin, labels, out);
}

// Round 2
// 116.585 us; speedup vs baseline: 1.1264x; 1.1264x over previous
//
#include <hip/hip_runtime.h>

// Problem constants
#define B_DIM   4096
#define C_DIM   128
#define P_IDS   256          // B/K_INST
#define INV_TEMP 20.0f       // 1/0.05
#define EPS 1e-6f

typedef unsigned short u16;
typedef __attribute__((ext_vector_type(8))) short bf16x8;
typedef __attribute__((ext_vector_type(4))) float f32x4;

__device__ __forceinline__ u16 f2bf(float x) {
    union { float f; unsigned u; } v; v.f = x;
    unsigned r = v.u + 0x7fffu + ((v.u >> 16) & 1u);   // RTN-even
    return (u16)(r >> 16);
}

// ---------------- kernel 1: fp32 -> bf16 fragment-tiled A ----------------
// A_t chunk c (16B = 8 bf16): grow=c>>8, kk=(c>>6)&3, lane=c&63, g=lane>>4,
// r=lane&15 -> holds A[grow*16 + r][kk*32 + g*8 .. +8].
// phase1's per-step fragment load (s, kk) is then lane-contiguous 1 KB.
__global__ __launch_bounds__(256) void convert_bf16(const float* __restrict__ feats,
                                                    u16* __restrict__ A_t) {
    const int c = blockIdx.x * 256 + threadIdx.x;       // 65536 chunks
    const int grow = c >> 8, kk = (c >> 6) & 3, lane = c & 63;
    const int g = lane >> 4, r = lane & 15;
    const float* src = feats + (size_t)(grow * 16 + r) * C_DIM + kk * 32 + g * 8;
    float4 u0 = *(const float4*)src;
    float4 u1 = *(const float4*)(src + 4);
    bf16x8 o;
    o[0] = (short)f2bf(u0.x); o[1] = (short)f2bf(u0.y);
    o[2] = (short)f2bf(u0.z); o[3] = (short)f2bf(u0.w);
    o[4] = (short)f2bf(u1.x); o[5] = (short)f2bf(u1.y);
    o[6] = (short)f2bf(u1.z); o[7] = (short)f2bf(u1.w);
    *(bf16x8*)(A_t + (size_t)c * 8) = o;
}

// ---------------- kernel 2: barrier-free streaming sim + max/min ----------------
// R10 vs R9 (131 us, phase1 59.4, MfmaUtil 22) / R8 (115 us, phase1 44.7, MfmaUtil 29):
//  * NO per-iter barriers, NO A-LDS, NO DMA, NO vmcnt drains. A streams
//    global(L2)->register in fragment-tiled layout (pre-transformed by
//    convert_bf16), double-buffered one 16-row step ahead. Waves free-run.
//  * B panel (16x reuse) staged once through 32 KB LDS (one __syncthreads),
//    then lives in 64 VGPRs. Cuts per-block B fp32 traffic 4x vs R9.
//  * pmax transposed to [row][wn][p]: phase1 stores 16-lane scatter
//    (fire-and-forget), phase2 reads fully coalesced.
// Grid (256 p, 4 h), 256 thr (4 waves: wm=row-half of 1024, wn=col-half).
// Per wave: 32 steps x {4 global_load_dwordx4, 16 MFMA, fold+2 shfl, store}.
__global__ __launch_bounds__(256, 3) void phase1(const u16*  __restrict__ A_t,   // frag-tiled bf16 [65536 chunks]
                                                 const float* __restrict__ Bm32, // fp32 [32768][128]
                                                 float* __restrict__ pmax,       // [4096][2][256]
                                                 float* __restrict__ pmin)       // [2][4096]
{
    __shared__ u16 Bls[2048 * 8];     // 32 KB: B panel, fragment-tiled

    const int tid  = threadIdx.x;
    const int lane = tid & 63;
    const int wave = tid >> 6;
    const int wm   = wave >> 1;       // row half of block's 1024 rows
    const int wn   = wave & 1;        // col half (64 of 128 support cols)
    const int p    = blockIdx.x;      // identity 0..255
    const int h    = blockIdx.y;      // row quarter: rows h*1024..+1023

    // ---- one-time: stage B panel (rows p*128..+127, all 128 k) into LDS,
    //      fragment-tiled exactly like A_t (chunk = (ngrp*4+kk)*64 + lane) ----
#pragma unroll
    for (int j = 0; j < 8; ++j) {
        const int c    = j * 256 + tid;          // 0..2047
        const int ngrp = c >> 8, kk = (c >> 6) & 3, lc = c & 63;
        const int gg   = lc >> 4, rr = lc & 15;
        const float* src = Bm32 + (size_t)(p * 128 + ngrp * 16 + rr) * C_DIM + kk * 32 + gg * 8;
        float4 u0 = *(const float4*)src;
        float4 u1 = *(const float4*)(src + 4);
        bf16x8 o;
        o[0] = (short)f2bf(u0.x); o[1] = (short)f2bf(u0.y);
        o[2] = (short)f2bf(u0.z); o[3] = (short)f2bf(u0.w);
        o[4] = (short)f2bf(u1.x); o[5] = (short)f2bf(u1.y);
        o[6] = (short)f2bf(u1.z); o[7] = (short)f2bf(u1.w);
        *(bf16x8*)&Bls[c * 8] = o;
    }
    __syncthreads();                  // the ONLY barrier in the kernel

    // ---- B fragments -> registers (64 VGPRs), one-time ----
    bf16x8 b[4][4];                   // [ni][kk]; rows p*128 + wn*64 + ni*16 + r
#pragma unroll
    for (int ni = 0; ni < 4; ++ni)
#pragma unroll
        for (int kk = 0; kk < 4; ++kk)
            b[ni][kk] = *(const bf16x8*)&Bls[(((wn * 4 + ni) * 4 + kk) * 64 + lane) * 8];

    // ---- A stream addressing: 32 steps of 16 rows ----
    const int grow0 = h * 64 + wm * 32;                       // global row-group base
    const u16* abase = A_t + ((size_t)grow0 * 256 + lane) * 8; // +s*2048, +kk*512 (u16)

    const int rbase = h * 1024 + wm * 512;
    float* const pq = pmax + (size_t)rbase * 512 + wn * 256 + p;  // + (s*16+lane)*512
    const bool dhit = (h == (p >> 6)) && (wm == ((p >> 5) & 1));
    const int  ssel = p & 31;

#define LOADA(dst, ss) do { const u16* ap = abase + (size_t)(ss) * 2048;         \
        dst[0] = *(const bf16x8*)ap;         dst[1] = *(const bf16x8*)(ap + 512); \
        dst[2] = *(const bf16x8*)(ap + 1024); dst[3] = *(const bf16x8*)(ap + 1536); } while (0)

    // D[n][m] per lane (operands swapped): col(lane&15)=A-row, row(g*4+rr)=B-col
#define STEP(areg, ss) do {                                                       \
        f32x4 acc[4] = {};                                                        \
        _Pragma("unroll")                                                         \
        for (int kk = 0; kk < 4; ++kk) {                                          \
            _Pragma("unroll")                                                     \
            for (int ni = 0; ni < 4; ++ni)                                        \
                acc[ni] = __builtin_amdgcn_mfma_f32_16x16x32_bf16(                \
                    b[ni][kk], areg[kk], acc[ni], 0, 0, 0);                       \
        }                                                                         \
        float mx = acc[0][0];                                                     \
        _Pragma("unroll")                                                         \
        for (int ni = 0; ni < 4; ++ni)                                            \
            _Pragma("unroll")                                                     \
            for (int rr = 0; rr < 4; ++rr)                                        \
                if (ni || rr) mx = fmaxf(mx, acc[ni][rr]);                        \
        mx = fmaxf(mx, __shfl_xor(mx, 16, 64));                                   \
        mx = fmaxf(mx, __shfl_xor(mx, 32, 64));                                   \
        if (lane < 16) pq[(size_t)((ss) * 16 + lane) * 512] = mx;                 \
        if (dhit && (ss) == ssel) {                                               \
            float mn = acc[0][0];                                                 \
            _Pragma("unroll")                                                     \
            for (int ni = 0; ni < 4; ++ni)                                        \
                _Pragma("unroll")                                                 \
                for (int rr = 0; rr < 4; ++rr)                                    \
                    if (ni || rr) mn = fminf(mn, acc[ni][rr]);                    \
            mn = fminf(mn, __shfl_xor(mn, 16, 64));                               \
            mn = fminf(mn, __shfl_xor(mn, 32, 64));                               \
            if (lane < 16) pmin[wn * B_DIM + p * 16 + lane] = mn;                 \
        }                                                                         \
    } while (0)

    bf16x8 aA[4], aB[4];
    LOADA(aA, 0);
#pragma unroll 1
    for (int s = 0; s < 32; s += 2) {
        LOADA(aB, s + 1);             // prefetch odd step
        STEP(aA, s);
        if (s + 2 < 32) LOADA(aA, s + 2);  // prefetch next even step
        STEP(aB, s + 1);
    }
#undef LOADA
#undef STEP
}

// ---------------- kernel 3: per-row loss + mean ----------------
// pmax now [row][wn][p]: one wave per row, 8 coalesced 256B reads.
__global__ __launch_bounds__(256) void phase2(const float* __restrict__ pmax,  // [4096][2][256]
                                              const float* __restrict__ pmin,  // [2][4096]
                                              const int* __restrict__ labels,
                                              float* __restrict__ out) {
    const int tid  = threadIdx.x;
    const int lane = tid & 63;
    const int wave = tid >> 6;
    float wsum = 0.f;
#pragma unroll
    for (int rw = 0; rw < 4; ++rw) {
        const int row = blockIdx.x * 16 + wave * 4 + rw;
        const int pid = labels[row];
        const float* q = pmax + (size_t)row * 512;
        float s = 0.f;
#pragma unroll
        for (int k = 0; k < 4; ++k) {
            const int pp = k * 64 + lane;                    // identity index
            const float v = fmaxf(q[pp], q[256 + pp]);       // fold wn halves BEFORE exp
            s += (pp == pid) ? 0.f : __expf(v * INV_TEMP);
        }
        s += __shfl_xor(s, 1, 64);  s += __shfl_xor(s, 2, 64);
        s += __shfl_xor(s, 4, 64);  s += __shfl_xor(s, 8, 64);
        s += __shfl_xor(s, 16, 64); s += __shfl_xor(s, 32, 64);
        if (lane == 0) {
            const float mn  = fminf(pmin[row], pmin[B_DIM + row]);
            const float pos = __expf(mn * INV_TEMP);
            wsum += -__logf(pos / (pos + s + EPS) + EPS);
        }
    }
    __shared__ float part[4];
    if (lane == 0) part[wave] = wsum;
    __syncthreads();
    if (tid == 0)
        atomicAdd(out, (part[0] + part[1] + part[2] + part[3]) * (1.0f / (float)B_DIM));
}

extern "C" void kernel_launch(void* const* d_in, const int* in_sizes, int n_in,
                              void* d_out, int out_size, void* d_ws, size_t ws_size,
                              hipStream_t stream) {
    const float* feats   = (const float*)d_in[0];   // [4096,128]
    const float* feats_s = (const float*)d_in[1];   // [4096,8,128] fp32
    const int*   labels  = (const int*)d_in[2];     // [4096]
    float* out = (float*)d_out;

    // workspace: A_t (1 MB) | pmax (8 MB) | pmin (32 KB)
    u16* wsA = (u16*)d_ws;
    float* pmax = (float*)((char*)d_ws + (1u << 20));
    float* pmin = pmax + (size_t)B_DIM * 512;

    hipMemsetAsync(d_out, 0, sizeof(float), stream);
    convert_bf16<<<256, 256, 0, stream>>>(feats, wsA);
    dim3 g1(P_IDS, 4);
    phase1<<<g1, 256, 0, stream>>>(wsA, feats_s, pmax, pmin);
    phase2<<<B_DIM / 16, 256, 0, stream>>>(pmax, pmin, labels, out);
}

// Round 3
// 110.787 us; speedup vs baseline: 1.1854x; 1.0523x over previous
//
#include <hip/hip_runtime.h>

// Problem constants
#define B_DIM   4096
#define C_DIM   128
#define P_IDS   256          // B/K_INST
#define INV_TEMP 20.0f       // 1/0.05
#define EPS 1e-6f

typedef unsigned short u16;
typedef __attribute__((ext_vector_type(8))) short bf16x8;
typedef __attribute__((ext_vector_type(4))) float f32x4;

__device__ __forceinline__ u16 f2bf(float x) {
    union { float f; unsigned u; } v; v.f = x;
    unsigned r = v.u + 0x7fffu + ((v.u >> 16) & 1u);   // RTN-even
    return (u16)(r >> 16);
}

// ---------------- kernel 1: fp32 -> bf16 fragment-tiled A ----------------
// A_t chunk c (16B = 8 bf16): grow=c>>8, kk=(c>>6)&3, lane=c&63, g=lane>>4,
// r=lane&15 -> holds A[grow*16 + r][kk*32 + g*8 .. +8].
__global__ __launch_bounds__(256) void convert_bf16(const float* __restrict__ feats,
                                                    u16* __restrict__ A_t) {
    const int c = blockIdx.x * 256 + threadIdx.x;       // 65536 chunks
    const int grow = c >> 8, kk = (c >> 6) & 3, lane = c & 63;
    const int g = lane >> 4, r = lane & 15;
    const float* src = feats + (size_t)(grow * 16 + r) * C_DIM + kk * 32 + g * 8;
    float4 u0 = *(const float4*)src;
    float4 u1 = *(const float4*)(src + 4);
    bf16x8 o;
    o[0] = (short)f2bf(u0.x); o[1] = (short)f2bf(u0.y);
    o[2] = (short)f2bf(u0.z); o[3] = (short)f2bf(u0.w);
    o[4] = (short)f2bf(u1.x); o[5] = (short)f2bf(u1.y);
    o[6] = (short)f2bf(u1.z); o[7] = (short)f2bf(u1.w);
    *(bf16x8*)(A_t + (size_t)c * 8) = o;
}

// ---------------- kernel 2: barrier-free streaming sim + max/min ----------------
// R11 vs R10 (116.6 us, phase1 43.1, MfmaUtil 30, WRITE 65.6 MB):
//  * pmax reverted to [wn][p][row]: a wave's 16-lane store is one full
//    EXCLUSIVE 64B line (consecutive rows, fixed p). Kills the 8x write
//    amplification (65.6 -> ~8.4 MB WRITE_SIZE) and store backpressure.
//    phase2 coalescing recovered via stripe-transposed reads there.
// Retained from R10: no barriers / no A-LDS / no DMA (A streams global->reg
// in fragment-tiled layout, double-buffered), B panel staged once via 32 KB
// LDS then 64 VGPRs, swapped MFMA operands (per-A-row max = fold 16 + 2 shfl).
__global__ __launch_bounds__(256, 3) void phase1(const u16*  __restrict__ A_t,   // frag-tiled bf16 [65536 chunks]
                                                 const float* __restrict__ Bm32, // fp32 [32768][128]
                                                 float* __restrict__ pmax,       // [2][256][4096]
                                                 float* __restrict__ pmin)       // [2][4096]
{
    __shared__ u16 Bls[2048 * 8];     // 32 KB: B panel, fragment-tiled

    const int tid  = threadIdx.x;
    const int lane = tid & 63;
    const int wave = tid >> 6;
    const int wm   = wave >> 1;       // row half of block's 1024 rows
    const int wn   = wave & 1;        // col half (64 of 128 support cols)
    const int p    = blockIdx.x;      // identity 0..255
    const int h    = blockIdx.y;      // row quarter: rows h*1024..+1023

    // ---- one-time: stage B panel into LDS, fragment-tiled like A_t ----
#pragma unroll
    for (int j = 0; j < 8; ++j) {
        const int c    = j * 256 + tid;          // 0..2047
        const int ngrp = c >> 8, kk = (c >> 6) & 3, lc = c & 63;
        const int gg   = lc >> 4, rr = lc & 15;
        const float* src = Bm32 + (size_t)(p * 128 + ngrp * 16 + rr) * C_DIM + kk * 32 + gg * 8;
        float4 u0 = *(const float4*)src;
        float4 u1 = *(const float4*)(src + 4);
        bf16x8 o;
        o[0] = (short)f2bf(u0.x); o[1] = (short)f2bf(u0.y);
        o[2] = (short)f2bf(u0.z); o[3] = (short)f2bf(u0.w);
        o[4] = (short)f2bf(u1.x); o[5] = (short)f2bf(u1.y);
        o[6] = (short)f2bf(u1.z); o[7] = (short)f2bf(u1.w);
        *(bf16x8*)&Bls[c * 8] = o;
    }
    __syncthreads();                  // the ONLY barrier in the kernel

    // ---- B fragments -> registers (64 VGPRs), one-time ----
    bf16x8 b[4][4];                   // [ni][kk]; rows p*128 + wn*64 + ni*16 + r
#pragma unroll
    for (int ni = 0; ni < 4; ++ni)
#pragma unroll
        for (int kk = 0; kk < 4; ++kk)
            b[ni][kk] = *(const bf16x8*)&Bls[(((wn * 4 + ni) * 4 + kk) * 64 + lane) * 8];

    // ---- A stream addressing: 32 steps of 16 rows ----
    const int grow0 = h * 64 + wm * 32;                        // global row-group base
    const u16* abase = A_t + ((size_t)grow0 * 256 + lane) * 8; // +s*2048, +kk*512 (u16)

    // pmax [wn][p][row]: this wave owns rows h*1024 + wm*512 .. +511 at (wn,p)
    float* const pq = pmax + ((size_t)wn * P_IDS + p) * B_DIM + h * 1024 + wm * 512;
    const bool dhit = (h == (p >> 6)) && (wm == ((p >> 5) & 1));
    const int  ssel = p & 31;

#define LOADA(dst, ss) do { const u16* ap = abase + (size_t)(ss) * 2048;         \
        dst[0] = *(const bf16x8*)ap;         dst[1] = *(const bf16x8*)(ap + 512); \
        dst[2] = *(const bf16x8*)(ap + 1024); dst[3] = *(const bf16x8*)(ap + 1536); } while (0)

    // D[n][m] per lane (operands swapped): col(lane&15)=A-row, row(g*4+rr)=B-col
#define STEP(areg, ss) do {                                                       \
        f32x4 acc[4] = {};                                                        \
        _Pragma("unroll")                                                         \
        for (int kk = 0; kk < 4; ++kk) {                                          \
            _Pragma("unroll")                                                     \
            for (int ni = 0; ni < 4; ++ni)                                        \
                acc[ni] = __builtin_amdgcn_mfma_f32_16x16x32_bf16(                \
                    b[ni][kk], areg[kk], acc[ni], 0, 0, 0);                       \
        }                                                                         \
        float mx = acc[0][0];                                                     \
        _Pragma("unroll")                                                         \
        for (int ni = 0; ni < 4; ++ni)                                            \
            _Pragma("unroll")                                                     \
            for (int rr = 0; rr < 4; ++rr)                                        \
                if (ni || rr) mx = fmaxf(mx, acc[ni][rr]);                        \
        mx = fmaxf(mx, __shfl_xor(mx, 16, 64));                                   \
        mx = fmaxf(mx, __shfl_xor(mx, 32, 64));                                   \
        if (lane < 16) pq[(ss) * 16 + lane] = mx;                                 \
        if (dhit && (ss) == ssel) {                                               \
            float mn = acc[0][0];                                                 \
            _Pragma("unroll")                                                     \
            for (int ni = 0; ni < 4; ++ni)                                        \
                _Pragma("unroll")                                                 \
                for (int rr = 0; rr < 4; ++rr)                                    \
                    if (ni || rr) mn = fminf(mn, acc[ni][rr]);                    \
            mn = fminf(mn, __shfl_xor(mn, 16, 64));                               \
            mn = fminf(mn, __shfl_xor(mn, 32, 64));                               \
            if (lane < 16) pmin[wn * B_DIM + p * 16 + lane] = mn;                 \
        }                                                                         \
    } while (0)

    bf16x8 aA[4], aB[4];
    LOADA(aA, 0);
#pragma unroll 1
    for (int s = 0; s < 32; s += 2) {
        LOADA(aB, s + 1);             // prefetch odd step
        STEP(aA, s);
        if (s + 2 < 32) LOADA(aA, s + 2);  // prefetch next even step
        STEP(aB, s + 1);
    }
#undef LOADA
#undef STEP
}

// ---------------- kernel 3: per-row loss + mean (stripe-transposed reads) ----------------
// 64 blocks x 256 thr. Block owns a 64-row stripe; lane = row, wave owns a
// 64-wide p-range. Every pmax load is a coalesced 256B line (L2-resident).
__global__ __launch_bounds__(256) void phase2(const float* __restrict__ pmax,  // [2][256][4096]
                                              const float* __restrict__ pmin,  // [2][4096]
                                              const int* __restrict__ labels,
                                              float* __restrict__ out) {
    const int tid  = threadIdx.x;
    const int lane = tid & 63;
    const int wave = tid >> 6;
    const int row  = blockIdx.x * 64 + lane;
    const int pid  = labels[row];
    const float* q0 = pmax + (size_t)(wave * 64) * B_DIM + row;   // p = wave*64+j
    const float* q1 = q0 + (size_t)P_IDS * B_DIM;
    float s = 0.f;
#pragma unroll 8
    for (int j = 0; j < 64; ++j) {
        const int p  = wave * 64 + j;
        const float v = fmaxf(q0[(size_t)j * B_DIM], q1[(size_t)j * B_DIM]);
        s += (p == pid) ? 0.f : __expf(v * INV_TEMP);
    }
    __shared__ float part[4][64];
    part[wave][lane] = s;
    __syncthreads();
    if (wave == 0) {
        const float neg = part[0][lane] + part[1][lane] + part[2][lane] + part[3][lane];
        const float mn  = fminf(pmin[row], pmin[B_DIM + row]);
        const float pos = __expf(mn * INV_TEMP);
        float loss = -__logf(pos / (pos + neg + EPS) + EPS);
        loss += __shfl_xor(loss, 1, 64);
        loss += __shfl_xor(loss, 2, 64);
        loss += __shfl_xor(loss, 4, 64);
        loss += __shfl_xor(loss, 8, 64);
        loss += __shfl_xor(loss, 16, 64);
        loss += __shfl_xor(loss, 32, 64);
        if (lane == 0) atomicAdd(out, loss * (1.0f / (float)B_DIM));
    }
}

extern "C" void kernel_launch(void* const* d_in, const int* in_sizes, int n_in,
                              void* d_out, int out_size, void* d_ws, size_t ws_size,
                              hipStream_t stream) {
    const float* feats   = (const float*)d_in[0];   // [4096,128]
    const float* feats_s = (const float*)d_in[1];   // [4096,8,128] fp32
    const int*   labels  = (const int*)d_in[2];     // [4096]
    float* out = (float*)d_out;

    // workspace: A_t (1 MB) | pmax (8 MB) | pmin (32 KB)
    u16* wsA = (u16*)d_ws;
    float* pmax = (float*)((char*)d_ws + (1u << 20));
    float* pmin = pmax + (size_t)2 * P_IDS * B_DIM;

    hipMemsetAsync(d_out, 0, sizeof(float), stream);
    convert_bf16<<<256, 256, 0, stream>>>(feats, wsA);
    dim3 g1(P_IDS, 4);
    phase1<<<g1, 256, 0, stream>>>(wsA, feats_s, pmax, pmin);
    phase2<<<B_DIM / 64, 256, 0, stream>>>(pmax, pmin, labels, out);
}

// Round 5
// 109.555 us; speedup vs baseline: 1.1987x; 1.0112x over previous
//
#include <hip/hip_runtime.h>

// Problem constants
#define B_DIM   4096
#define C_DIM   128
#define P_IDS   256          // B/K_INST
#define INV_TEMP 20.0f       // 1/0.05
#define EPS 1e-6f

#define A_CHUNKS 65536       // 4096*128/8  (bf16x8 chunks)
#define B_CHUNKS 524288      // 32768*128/8
#define ALL_CHUNKS (A_CHUNKS + B_CHUNKS)

typedef unsigned short u16;
typedef __attribute__((ext_vector_type(8))) short bf16x8;
typedef __attribute__((ext_vector_type(4))) float f32x4;

__device__ __forceinline__ u16 f2bf(float x) {
    union { float f; unsigned u; } v; v.f = x;
    unsigned r = v.u + 0x7fffu + ((v.u >> 16) & 1u);   // RTN-even
    return (u16)(r >> 16);
}

// ---------------- kernel 1: fp32 -> bf16 fragment-tiled A and B ----------------
// Chunk c (16B = 8 bf16): grow=c2>>8, kk=(c2>>6)&3, lane=c2&63, g=lane>>4,
// r=lane&15 -> holds SRC[grow*16 + r][kk*32 + g*8 .. +8].
// Chunks 0..65535 = feats (A), 65536.. = feats_s (B). Boundary is block-aligned
// (65536/256 = 256), so the branch is block-uniform.
__global__ __launch_bounds__(256) void convert_bf16(const float* __restrict__ feats,
                                                    const float* __restrict__ feats_s,
                                                    u16* __restrict__ T) {
    const int c = blockIdx.x * 256 + threadIdx.x;
    const float* base; int c2;
    if (c < A_CHUNKS) { base = feats;   c2 = c; }
    else              { base = feats_s; c2 = c - A_CHUNKS; }
    const int grow = c2 >> 8, kk = (c2 >> 6) & 3, lane = c2 & 63;
    const int g = lane >> 4, r = lane & 15;
    const float* src = base + (size_t)(grow * 16 + r) * C_DIM + kk * 32 + g * 8;
    float4 u0 = *(const float4*)src;
    float4 u1 = *(const float4*)(src + 4);
    bf16x8 o;
    o[0] = (short)f2bf(u0.x); o[1] = (short)f2bf(u0.y);
    o[2] = (short)f2bf(u0.z); o[3] = (short)f2bf(u0.w);
    o[4] = (short)f2bf(u1.x); o[5] = (short)f2bf(u1.y);
    o[6] = (short)f2bf(u1.z); o[7] = (short)f2bf(u1.w);
    *(bf16x8*)(T + (size_t)c * 8) = o;
}

// ---------------- kernel 2: zero-LDS streaming sim + max/min ----------------
// R12 vs R11 (110.8 us, phase1 ~42, VGPR=64, LDS 32KB):
//  * VGPR_Count=64 in R11 proved the compiler kept B fragments in LDS and
//    re-read them EVERY step: 16 ds_read_b128/wave-step = ~98k cyc/CU = ~41 us
//    -> phase1 was LDS-read-throughput bound (conflict-free, so invisible in
//    SQ_LDS_BANK_CONFLICT; MfmaUtil 30 was the symptom).
//  * Fix: B pre-tiled to bf16 fragments by convert_bf16; phase1 loads its 16
//    B-fragments global->register ONCE. NO LDS object exists, so remat is
//    impossible -> b[4][4] must live in VGPRs (~140 total, 3 waves/SIMD).
//    Also deletes the 4x-redundant per-block B fp32 conversion and the last
//    __syncthreads.
//  * Epilogue fold: balanced tree (depth 4) instead of 15-deep serial fmax.
// Retained: barrier-free A streaming global->reg (fragment-tiled, double-
// buffered), swapped MFMA operands, [wn][p][row] pmax (exclusive 64B lines).
__global__ __launch_bounds__(256, 2) void phase1(const u16*  __restrict__ T,   // frag-tiled bf16: A then B
                                                 float* __restrict__ pmax,     // [2][256][4096]
                                                 float* __restrict__ pmin)     // [2][4096]
{
    const int tid  = threadIdx.x;
    const int lane = tid & 63;
    const int wave = tid >> 6;
    const int wm   = wave >> 1;       // row half of block's 1024 rows
    const int wn   = wave & 1;        // col half (64 of 128 support cols)
    const int p    = blockIdx.x;      // identity 0..255
    const int h    = blockIdx.y;      // row quarter: rows h*1024..+1023

    // ---- B fragments: 16 one-time global loads -> 64 VGPRs ----
    // chunk for (ni,kk) = ((p*8 + wn*4 + ni)*4 + kk)*64 + lane
    const u16* bbase = T + (size_t)A_CHUNKS * 8
                         + ((size_t)(p * 8 + wn * 4) * 256 + lane) * 8;
    bf16x8 b[4][4];                   // [ni][kk]
#pragma unroll
    for (int ni = 0; ni < 4; ++ni)
#pragma unroll
        for (int kk = 0; kk < 4; ++kk)
            b[ni][kk] = *(const bf16x8*)(bbase + ni * 2048 + kk * 512);

    // ---- A stream addressing: 32 steps of 16 rows ----
    const int grow0 = h * 64 + wm * 32;                      // global row-group base
    const u16* abase = T + ((size_t)grow0 * 256 + lane) * 8; // +s*2048, +kk*512 (u16)

    // pmax [wn][p][row]: this wave owns rows h*1024 + wm*512 .. +511 at (wn,p)
    float* const pq = pmax + ((size_t)wn * P_IDS + p) * B_DIM + h * 1024 + wm * 512;
    const bool dhit = (h == (p >> 6)) && (wm == ((p >> 5) & 1));
    const int  ssel = p & 31;

#define LOADA(dst, ss) do { const u16* ap = abase + (size_t)(ss) * 2048;         \
        dst[0] = *(const bf16x8*)ap;         dst[1] = *(const bf16x8*)(ap + 512); \
        dst[2] = *(const bf16x8*)(ap + 1024); dst[3] = *(const bf16x8*)(ap + 1536); } while (0)

    // D[n][m] per lane (operands swapped): col(lane&15)=A-row, row(g*4+rr)=B-col
#define STEP(areg, ss) do {                                                       \
        f32x4 acc[4] = {};                                                        \
        _Pragma("unroll")                                                         \
        for (int kk = 0; kk < 4; ++kk) {                                          \
            _Pragma("unroll")                                                     \
            for (int ni = 0; ni < 4; ++ni)                                        \
                acc[ni] = __builtin_amdgcn_mfma_f32_16x16x32_bf16(                \
                    b[ni][kk], areg[kk], acc[ni], 0, 0, 0);                       \
        }                                                                         \
        float t0 = fmaxf(fmaxf(acc[0][0], acc[0][1]), fmaxf(acc[0][2], acc[0][3]));\
        float t1 = fmaxf(fmaxf(acc[1][0], acc[1][1]), fmaxf(acc[1][2], acc[1][3]));\
        float t2 = fmaxf(fmaxf(acc[2][0], acc[2][1]), fmaxf(acc[2][2], acc[2][3]));\
        float t3 = fmaxf(fmaxf(acc[3][0], acc[3][1]), fmaxf(acc[3][2], acc[3][3]));\
        float mx = fmaxf(fmaxf(t0, t1), fmaxf(t2, t3));                           \
        mx = fmaxf(mx, __shfl_xor(mx, 16, 64));                                   \
        mx = fmaxf(mx, __shfl_xor(mx, 32, 64));                                   \
        if (lane < 16) pq[(ss) * 16 + lane] = mx;                                 \
        if (dhit && (ss) == ssel) {                                               \
            float n0 = fminf(fminf(acc[0][0], acc[0][1]), fminf(acc[0][2], acc[0][3]));\
            float n1 = fminf(fminf(acc[1][0], acc[1][1]), fminf(acc[1][2], acc[1][3]));\
            float n2 = fminf(fminf(acc[2][0], acc[2][1]), fminf(acc[2][2], acc[2][3]));\
            float n3 = fminf(fminf(acc[3][0], acc[3][1]), fminf(acc[3][2], acc[3][3]));\
            float mn = fminf(fminf(n0, n1), fminf(n2, n3));                       \
            mn = fminf(mn, __shfl_xor(mn, 16, 64));                               \
            mn = fminf(mn, __shfl_xor(mn, 32, 64));                               \
            if (lane < 16) pmin[wn * B_DIM + p * 16 + lane] = mn;                 \
        }                                                                         \
    } while (0)

    bf16x8 aA[4], aB[4];
    LOADA(aA, 0);
#pragma unroll 1
    for (int s = 0; s < 32; s += 2) {
        LOADA(aB, s + 1);             // prefetch odd step
        STEP(aA, s);
        if (s + 2 < 32) LOADA(aA, s + 2);  // prefetch next even step
        STEP(aB, s + 1);
    }
#undef LOADA
#undef STEP
}

// ---------------- kernel 3: per-row loss + mean (stripe-transposed reads) ----------------
// 64 blocks x 256 thr. Block owns a 64-row stripe; lane = row, wave owns a
// 64-wide p-range. Every pmax load is a coalesced 256B line (L2-resident).
__global__ __launch_bounds__(256) void phase2(const float* __restrict__ pmax,  // [2][256][4096]
                                              const float* __restrict__ pmin,  // [2][4096]
                                              const int* __restrict__ labels,
                                              float* __restrict__ out) {
    const int tid  = threadIdx.x;
    const int lane = tid & 63;
    const int wave = tid >> 6;
    const int row  = blockIdx.x * 64 + lane;
    const int pid  = labels[row];
    const float* q0 = pmax + (size_t)(wave * 64) * B_DIM + row;   // p = wave*64+j
    const float* q1 = q0 + (size_t)P_IDS * B_DIM;
    float s = 0.f;
#pragma unroll 8
    for (int j = 0; j < 64; ++j) {
        const int p  = wave * 64 + j;
        const float v = fmaxf(q0[(size_t)j * B_DIM], q1[(size_t)j * B_DIM]);
        s += (p == pid) ? 0.f : __expf(v * INV_TEMP);
    }
    __shared__ float part[4][64];
    part[wave][lane] = s;
    __syncthreads();
    if (wave == 0) {
        const float neg = part[0][lane] + part[1][lane] + part[2][lane] + part[3][lane];
        const float mn  = fminf(pmin[row], pmin[B_DIM + row]);
        const float pos = __expf(mn * INV_TEMP);
        float loss = -__logf(pos / (pos + neg + EPS) + EPS);
        loss += __shfl_xor(loss, 1, 64);
        loss += __shfl_xor(loss, 2, 64);
        loss += __shfl_xor(loss, 4, 64);
        loss += __shfl_xor(loss, 8, 64);
        loss += __shfl_xor(loss, 16, 64);
        loss += __shfl_xor(loss, 32, 64);
        if (lane == 0) atomicAdd(out, loss * (1.0f / (float)B_DIM));
    }
}

extern "C" void kernel_launch(void* const* d_in, const int* in_sizes, int n_in,
                              void* d_out, int out_size, void* d_ws, size_t ws_size,
                              hipStream_t stream) {
    const float* feats   = (const float*)d_in[0];   // [4096,128]
    const float* feats_s = (const float*)d_in[1];   // [4096,8,128] fp32
    const int*   labels  = (const int*)d_in[2];     // [4096]
    float* out = (float*)d_out;

    // workspace: T = frag-tiled bf16 A(1 MB)+B(8 MB) | pmax (8 MB) | pmin (32 KB)
    u16* T = (u16*)d_ws;
    float* pmax = (float*)((char*)d_ws + (16u << 20));
    float* pmin = pmax + (size_t)2 * P_IDS * B_DIM;

    hipMemsetAsync(d_out, 0, sizeof(float), stream);
    convert_bf16<<<ALL_CHUNKS / 256, 256, 0, stream>>>(feats, feats_s, T);
    dim3 g1(P_IDS, 4);
    phase1<<<g1, 256, 0, stream>>>(T, pmax, pmin);
    phase2<<<B_DIM / 64, 256, 0, stream>>>(pmax, pmin, labels, out);
}